// Round 15
// baseline (209.495 us; speedup 1.0000x reference)
//
#include <hip/hip_runtime.h>
#include <hip/hip_bf16.h>
#include <stdint.h>

typedef __attribute__((ext_vector_type(8))) short short8;
typedef __attribute__((ext_vector_type(4))) float f32x4;

union FragU { short8 s; __hip_bfloat162 h[4]; };
union BU { uint4 u; short8 s; };

__device__ __forceinline__ unsigned short f2bf(float f) {
  union { float f; unsigned int u; } v; v.f = f;
  unsigned int r = v.u + 0x7fffu + ((v.u >> 16) & 1u);
  return (unsigned short)(r >> 16);
}
__device__ __forceinline__ float bf2f(unsigned short h) {
  union { unsigned int u; float f; } v; v.u = ((unsigned int)h) << 16;
  return v.f;
}

// async global -> LDS, 16B per lane. LDS dest = uniform base + lane*16 (linear).
#define GLOAD_LDS16(gp, lp) \
  __builtin_amdgcn_global_load_lds((const __attribute__((address_space(1))) void*)(gp), \
                                   (__attribute__((address_space(3))) void*)(lp), 16, 0, 0)

// ---------------------------------------------------------------------------
// Kernel 0 (grid 80 x 256):
//   blocks 0..63 : bTf = relGW (= rel @ GW) packed in MFMA-fragment order.
//   blocks 64..79: tree attention (4 trees per block, one per wave) -> tree_emb.
// (accums zeroed by hipMemsetAsync before this kernel.)
// ---------------------------------------------------------------------------
__global__ void k_prep(const float* __restrict__ rel, const float* __restrict__ GW,
                       unsigned short* __restrict__ bTf,
                       const float* __restrict__ col_table, const float* __restrict__ rel_table,
                       const float* __restrict__ Wk, const float* __restrict__ Wq,
                       const float* __restrict__ Wv,
                       const int* __restrict__ table_ids, const int* __restrict__ l_ids,
                       const int* __restrict__ r_ids, float* __restrict__ tree_emb) {
  __shared__ union {
    struct { float tile[64][65]; float gws[64][64]; float relgw[64][64]; } p;  // ~48.3 KB
    struct { unsigned short W3b[3 * 4096]; float qT[4][64][4]; } tr;           // 28 KB
  } sm;
  const int t = threadIdx.x;
  const int lane = t & 63;
  const int wid = t >> 6;

  if (blockIdx.x < 64) {
    // ----------------------- bTf pack branch -----------------------
    const int j = blockIdx.x;
#pragma unroll
    for (int p = 0; p < 16; ++p) {
      int elem = p * 256 + t;
      int kk = elem >> 6, ee = elem & 63;
      sm.p.tile[kk][ee] = rel[(j * 64 + kk) * 64 + ee];
      ((float*)sm.p.gws)[elem] = GW[elem];
    }
    __syncthreads();
    {
      const int e = t >> 2, chunk = t & 3;
      for (int i = 0; i < 16; ++i) {
        float acc = 0.f;
#pragma unroll
        for (int ii = 0; ii < 64; ++ii) acc += sm.p.tile[chunk * 16 + i][ii] * sm.p.gws[ii][e];
        sm.p.relgw[chunk * 16 + i][e] = acc;
      }
    }
    __syncthreads();
#pragma unroll
    for (int m = 0; m < 2; ++m) {
      const int f = t * 2 + m;
      const int nt = f >> 7, kc = (f >> 6) & 1, ln = f & 63;
      const int g = ln >> 4, r = ln & 15;
      union { unsigned short u16[8]; uint4 v; } pk;
#pragma unroll
      for (int s = 0; s < 8; ++s) pk.u16[s] = f2bf(sm.p.relgw[kc * 32 + g * 8 + s][nt * 16 + r]);
      *(uint4*)(bTf + (size_t)j * 4096 + f * 8) = pk.v;
    }
  } else {
    // ------------------------- tree branch -------------------------
    const int e = lane;
    for (int i = t; i < 3 * 4096; i += 256) {
      float v;
      if (i < 4096) v = Wk[i];
      else if (i < 8192) v = Wq[i - 4096];
      else v = Wv[i - 8192];
      sm.tr.W3b[i] = f2bf(v);
    }
    __syncthreads();

    const int tree = (blockIdx.x - 64) * 4 + wid;   // 0..63
    const int b = tree >> 3;
    const int* tid = table_ids + tree * 17;
    const int* lid = l_ids + tree * 32;
    const int* rid = r_ids + tree * 32;

    float prev = rel_table[tid[0] * 64 + e];

    for (int d = 0; d < 16; ++d) {
      const int l0 = lid[d * 2], l1 = lid[d * 2 + 1];
      const int r0 = rid[d * 2], r1 = rid[d * 2 + 1];
      const float lce = 0.5f * (col_table[l0 * 64 + e] + col_table[l1 * 64 + e]);
      const float rce = 0.5f * (col_table[r0 * 64 + e] + col_table[r1 * 64 + e]);
      const float rte = rel_table[tid[1 + d] * 64 + e];
      float4 qv0; qv0.x = prev; qv0.y = lce; qv0.z = rce; qv0.w = rte;
      *(float4*)&sm.tr.qT[wid][e][0] = qv0;
      __syncthreads();

      float K[4] = {0, 0, 0, 0}, Q[4] = {0, 0, 0, 0}, V[4] = {0, 0, 0, 0};
#pragma unroll 8
      for (int i = 0; i < 64; ++i) {
        const f32x4 qv = *(const f32x4*)&sm.tr.qT[wid][i][0];
        const float wk = bf2f(sm.tr.W3b[i * 64 + e]);
        const float wq = bf2f(sm.tr.W3b[4096 + i * 64 + e]);
        const float wvv = bf2f(sm.tr.W3b[8192 + i * 64 + e]);
#pragma unroll
        for (int j = 0; j < 4; ++j) {
          K[j] += qv[j] * wk;
          Q[j] += qv[j] * wq;
          V[j] += qv[j] * wvv;
        }
      }

      float sc[4][4];
#pragma unroll
      for (int j = 0; j < 4; ++j)
#pragma unroll
        for (int k = 0; k < 4; ++k) {
          float p = Q[j] * K[k];
          p += __shfl_xor(p, 1);  p += __shfl_xor(p, 2);  p += __shfl_xor(p, 4);
          p += __shfl_xor(p, 8);  p += __shfl_xor(p, 16); p += __shfl_xor(p, 32);
          sc[j][k] = p * (1.f / 64.f);
        }

      float wsum[4] = {0, 0, 0, 0};
#pragma unroll
      for (int j = 0; j < 4; ++j) {
        float mx = fmaxf(fmaxf(sc[j][0], sc[j][1]), fmaxf(sc[j][2], sc[j][3]));
        float a0 = __expf(sc[j][0] - mx), a1 = __expf(sc[j][1] - mx);
        float a2 = __expf(sc[j][2] - mx), a3 = __expf(sc[j][3] - mx);
        float inv = 1.f / (a0 + a1 + a2 + a3);
        wsum[0] += a0 * inv; wsum[1] += a1 * inv; wsum[2] += a2 * inv; wsum[3] += a3 * inv;
      }

      prev = wsum[0] * V[0] + wsum[1] * V[1] + wsum[2] * V[2] + wsum[3] * V[3];
      __syncthreads();
    }
    atomicAdd(&tree_emb[b * 64 + e], prev);
  }
}

// ---------------------------------------------------------------------------
// Kernel 1 (grid 512 x 256, pure GEMM — exactly fills 2 blocks/CU, no tail):
//   C = link[b][64 rows] @ relGW  (K=4096, cols=64)
//   BARRIER-FREE per-wave pipeline, BK=128 (512B DRAM runs per row visit).
//   A: 8 global_load_lds/tile into wave-private 2x8KB LDS ring.
//   B: fragment-packed bTf to registers (16 uint4), single-buffered.
//   Steady: LOADB(t) -> STAGEA(t+1) -> vmcnt(8) -> COMPUTE(t).
// ---------------------------------------------------------------------------
__global__ __launch_bounds__(256, 2) void k_main(
    const float* __restrict__ link, const unsigned short* __restrict__ bTf,
    const float* __restrict__ gbias, float* __restrict__ pooled_sum) {
  __shared__ char aLds[4][2][8192];    // 64 KB

  const int t = threadIdx.x;
  const int lane = t & 63;
  const int wid = t >> 6;            // 0..3

  const int gid = blockIdx.x;               // 0..511
  const int b = gid >> 6;                   // batch
  const int rb = gid & 63;                  // 64-row block
  const int rowG0 = rb * 64 + wid * 16;     // this wave's first row
  const int phase = (gid * 4 + wid + b * 9) & 31;   // 32 tiles of 128k
  const int g = lane >> 4;                  // k-group 0..3
  const int r = lane & 15;                  // row/col within fragment
  const uint32_t fr = (uint32_t)((r & 7) << 4);

  const char* linkb = (const char*)(link + ((size_t)b << 24));
  const char* bTfb = (const char*)bTf;
  const int a_r2 = lane >> 5;                       // 0..1
  const uint32_t a_wb = (uint32_t)((lane & 31) * 16);

  char* a0buf = aLds[wid][0];
  char* a1buf = aLds[wid][1];

  f32x4 acc[4];
#pragma unroll
  for (int nt = 0; nt < 4; ++nt) acc[nt] = (f32x4){0.f, 0.f, 0.f, 0.f};
  uint4 bq[16];

#define STAGEA(ab_, tta) do {                                              \
    const size_t ka = (size_t)(tta) * 512;  /* 128k * 4B per row */        \
    _Pragma("unroll")                                                      \
    for (int j = 0; j < 8; ++j) {                                          \
      const int wlrow = 2 * j + a_r2;                                      \
      const uint32_t cb = a_wb ^ ((uint32_t)(wlrow & 7) << 4);             \
      GLOAD_LDS16(linkb + (size_t)(rowG0 + wlrow) * 16384 + ka + cb,       \
                  (ab_) + j * 1024);                                       \
    }                                                                      \
  } while (0)

#define LOADB(tta) do {                                                    \
    const char* bb = bTfb + (size_t)(tta) * 16384 + lane * 16;             \
    _Pragma("unroll")                                                      \
    for (int j = 0; j < 8; ++j) {                                          \
      bq[j]     = *(const uint4*)(bb + j * 1024);                          \
      bq[8 + j] = *(const uint4*)(bb + 8192 + j * 1024);                   \
    }                                                                      \
  } while (0)

#define COMPUTEW(ab_) do {                                                 \
    const char* ar = (ab_) + r * 512;                                      \
    _Pragma("unroll")                                                      \
    for (int kh = 0; kh < 2; ++kh) {                                       \
      _Pragma("unroll")                                                    \
      for (int kc = 0; kc < 2; ++kc) {                                     \
        const uint32_t o0 = ((uint32_t)(kh * 256 + kc * 128 + g * 32)) ^ fr; \
        const f32x4 a0 = *(const f32x4*)(ar + o0);                         \
        const f32x4 a1 = *(const f32x4*)(ar + (o0 ^ 16));                  \
        FragU f;                                                           \
        f.h[0] = __float22bfloat162_rn(float2{a0[0], a0[1]});              \
        f.h[1] = __float22bfloat162_rn(float2{a0[2], a0[3]});              \
        f.h[2] = __float22bfloat162_rn(float2{a1[0], a1[1]});              \
        f.h[3] = __float22bfloat162_rn(float2{a1[2], a1[3]});              \
        _Pragma("unroll")                                                  \
        for (int nt = 0; nt < 4; ++nt) {                                   \
          BU bu; bu.u = bq[kh * 8 + nt * 2 + kc];                          \
          acc[nt] = __builtin_amdgcn_mfma_f32_16x16x32_bf16(f.s, bu.s, acc[nt], 0, 0, 0); \
        }                                                                  \
      }                                                                    \
    }                                                                      \
  } while (0)

  STAGEA(a0buf, phase);                  // tile 0 into buf0
  for (int it2 = 0; it2 < 16; ++it2) {
    const int te = 2 * it2;
    // even tile -> buf0
    LOADB((te + phase) & 31);
    STAGEA(a1buf, (te + 1 + phase) & 31);
    asm volatile("s_waitcnt vmcnt(8)" ::: "memory");   // A(te),B(te) done; A(te+1) in flight
    COMPUTEW(a0buf);
    // odd tile -> buf1
    LOADB((te + 1 + phase) & 31);
    if (it2 < 15) {
      STAGEA(a0buf, (te + 2 + phase) & 31);
      asm volatile("s_waitcnt vmcnt(8)" ::: "memory");
    } else {
      asm volatile("s_waitcnt vmcnt(0)" ::: "memory");
    }
    COMPUTEW(a1buf);
  }

  // ---- epilogue: relu(C + bias) colsum over this wave's 16 rows ----
#pragma unroll
  for (int nt = 0; nt < 4; ++nt) {
    const float gbv = gbias[nt * 16 + r];
    float s = 0.f;
#pragma unroll
    for (int j = 0; j < 4; ++j) s += fmaxf(acc[nt][j] + gbv, 0.f);
    s += __shfl_xor(s, 16);
    s += __shfl_xor(s, 32);
    if (g == 0) atomicAdd(&pooled_sum[b * 64 + nt * 16 + r], s);
  }
}

// ---------------------------------------------------------------------------
// Kernel 2: logits = [pooled_sum/4096 || tree_emb] @ fc_w  + clip(log(mask))
// grid 128 x 256
// ---------------------------------------------------------------------------
__global__ void k_final(const float* __restrict__ action_mask, const float* __restrict__ fc_w,
                        const float* __restrict__ pooled_sum, const float* __restrict__ tree_emb,
                        float* __restrict__ out) {
  __shared__ float c[128];
  const int b = blockIdx.x >> 4;
  const int a = ((blockIdx.x & 15) << 8) + threadIdx.x;
  if (threadIdx.x < 128) {
    c[threadIdx.x] = (threadIdx.x < 64) ? pooled_sum[b * 64 + threadIdx.x] * (1.f / 4096.f)
                                        : tree_emb[b * 64 + threadIdx.x - 64];
  }
  __syncthreads();
  float acc = 0.f;
  for (int i = 0; i < 128; ++i) acc += c[i] * fc_w[i * 4096 + a];
  const float m = action_mask[b * 4096 + a];
  float lg = __logf(m);
  lg = fminf(fmaxf(lg, -3.4e38f), 3.4e38f);
  out[b * 4096 + a] = lg + acc;
}

// ---------------------------------------------------------------------------
extern "C" void kernel_launch(void* const* d_in, const int* in_sizes, int n_in,
                              void* d_out, int out_size, void* d_ws, size_t ws_size,
                              hipStream_t stream) {
  const float* link = (const float*)d_in[0];
  const float* mask = (const float*)d_in[1];
  const float* col = (const float*)d_in[2];
  const float* rel = (const float*)d_in[3];
  const float* GW = (const float*)d_in[4];
  const float* gb = (const float*)d_in[5];
  const float* Wk = (const float*)d_in[6];
  const float* Wq = (const float*)d_in[7];
  const float* Wv = (const float*)d_in[8];
  const float* fcw = (const float*)d_in[9];
  const int* tids = (const int*)d_in[10];
  const int* lids = (const int*)d_in[11];
  const int* rids = (const int*)d_in[12];
  float* out = (float*)d_out;

  unsigned short* bTf = (unsigned short*)d_ws;              // 512 KB (frag-packed relGW)
  float* accums = (float*)((char*)d_ws + 512 * 1024);       // 1024 floats
  float* pooled_sum = accums;                               // [8][64]
  float* tree = accums + 512;                               // [8][64]

  hipMemsetAsync(accums, 0, 1024 * sizeof(float), stream);
  hipLaunchKernelGGL(k_prep, dim3(80), dim3(256), 0, stream,
                     rel, GW, bTf, col, rel, Wk, Wq, Wv, tids, lids, rids, tree);
  hipLaunchKernelGGL(k_main, dim3(512), dim3(256), 0, stream,
                     link, bTf, gb, pooled_sum);
  hipLaunchKernelGGL(k_final, dim3(128), dim3(256), 0, stream, mask, fcw, pooled_sum, tree, out);
}

// Round 16
// 203.705 us; speedup vs baseline: 1.0284x; 1.0284x over previous
//
#include <hip/hip_runtime.h>
#include <hip/hip_bf16.h>
#include <stdint.h>

typedef __attribute__((ext_vector_type(8))) short short8;
typedef __attribute__((ext_vector_type(4))) float f32x4;

union FragU { short8 s; __hip_bfloat162 h[4]; };
union BU { uint4 u; short8 s; };

__device__ __forceinline__ unsigned short f2bf(float f) {
  union { float f; unsigned int u; } v; v.f = f;
  unsigned int r = v.u + 0x7fffu + ((v.u >> 16) & 1u);
  return (unsigned short)(r >> 16);
}
__device__ __forceinline__ float bf2f(unsigned short h) {
  union { unsigned int u; float f; } v; v.u = ((unsigned int)h) << 16;
  return v.f;
}

// async global -> LDS, 16B per lane. LDS dest = uniform base + lane*16 (linear).
#define GLOAD_LDS16(gp, lp) \
  __builtin_amdgcn_global_load_lds((const __attribute__((address_space(1))) void*)(gp), \
                                   (__attribute__((address_space(3))) void*)(lp), 16, 0, 0)

// ---------------------------------------------------------------------------
// Kernel 0 (grid 80 x 256):
//   blocks 0..63 : bTf = relGW (= rel @ GW) packed in MFMA-fragment order.
//                  block 0 also zeros pooled_sum (512 floats) — safe, k_main
//                  launches after ALL of k_prep.
//   blocks 64..79: tree attention (4 trees per block, one per wave) ->
//                  PLAIN STORES to treeS[tree][64] (one writer per tree,
//                  no atomics, no zero-init; k_final sums the 8 trees per b).
// ---------------------------------------------------------------------------
__global__ void k_prep(const float* __restrict__ rel, const float* __restrict__ GW,
                       unsigned short* __restrict__ bTf, float* __restrict__ pooled_sum,
                       const float* __restrict__ col_table, const float* __restrict__ rel_table,
                       const float* __restrict__ Wk, const float* __restrict__ Wq,
                       const float* __restrict__ Wv,
                       const int* __restrict__ table_ids, const int* __restrict__ l_ids,
                       const int* __restrict__ r_ids, float* __restrict__ treeS) {
  __shared__ union {
    struct { float tile[64][65]; float gws[64][64]; float relgw[64][64]; } p;  // ~48.3 KB
    struct { unsigned short W3b[3 * 4096]; float qT[4][64][4]; } tr;           // 28 KB
  } sm;
  const int t = threadIdx.x;
  const int lane = t & 63;
  const int wid = t >> 6;

  if (blockIdx.x < 64) {
    // ----------------------- bTf pack branch -----------------------
    const int j = blockIdx.x;
    if (j == 0) { pooled_sum[t] = 0.f; pooled_sum[t + 256] = 0.f; }
#pragma unroll
    for (int p = 0; p < 16; ++p) {
      int elem = p * 256 + t;
      int kk = elem >> 6, ee = elem & 63;
      sm.p.tile[kk][ee] = rel[(j * 64 + kk) * 64 + ee];
      ((float*)sm.p.gws)[elem] = GW[elem];
    }
    __syncthreads();
    {
      const int e = t >> 2, chunk = t & 3;
      for (int i = 0; i < 16; ++i) {
        float acc = 0.f;
#pragma unroll
        for (int ii = 0; ii < 64; ++ii) acc += sm.p.tile[chunk * 16 + i][ii] * sm.p.gws[ii][e];
        sm.p.relgw[chunk * 16 + i][e] = acc;
      }
    }
    __syncthreads();
#pragma unroll
    for (int m = 0; m < 2; ++m) {
      const int f = t * 2 + m;
      const int nt = f >> 7, kc = (f >> 6) & 1, ln = f & 63;
      const int g = ln >> 4, r = ln & 15;
      union { unsigned short u16[8]; uint4 v; } pk;
#pragma unroll
      for (int s = 0; s < 8; ++s) pk.u16[s] = f2bf(sm.p.relgw[kc * 32 + g * 8 + s][nt * 16 + r]);
      *(uint4*)(bTf + (size_t)j * 4096 + f * 8) = pk.v;
    }
  } else {
    // ------------------------- tree branch -------------------------
    const int e = lane;
    for (int i = t; i < 3 * 4096; i += 256) {
      float v;
      if (i < 4096) v = Wk[i];
      else if (i < 8192) v = Wq[i - 4096];
      else v = Wv[i - 8192];
      sm.tr.W3b[i] = f2bf(v);
    }
    __syncthreads();

    const int tree = (blockIdx.x - 64) * 4 + wid;   // 0..63
    const int* tid = table_ids + tree * 17;
    const int* lid = l_ids + tree * 32;
    const int* rid = r_ids + tree * 32;

    float prev = rel_table[tid[0] * 64 + e];

    for (int d = 0; d < 16; ++d) {
      const int l0 = lid[d * 2], l1 = lid[d * 2 + 1];
      const int r0 = rid[d * 2], r1 = rid[d * 2 + 1];
      const float lce = 0.5f * (col_table[l0 * 64 + e] + col_table[l1 * 64 + e]);
      const float rce = 0.5f * (col_table[r0 * 64 + e] + col_table[r1 * 64 + e]);
      const float rte = rel_table[tid[1 + d] * 64 + e];
      float4 qv0; qv0.x = prev; qv0.y = lce; qv0.z = rce; qv0.w = rte;
      *(float4*)&sm.tr.qT[wid][e][0] = qv0;
      __syncthreads();

      float K[4] = {0, 0, 0, 0}, Q[4] = {0, 0, 0, 0}, V[4] = {0, 0, 0, 0};
#pragma unroll 8
      for (int i = 0; i < 64; ++i) {
        const f32x4 qv = *(const f32x4*)&sm.tr.qT[wid][i][0];
        const float wk = bf2f(sm.tr.W3b[i * 64 + e]);
        const float wq = bf2f(sm.tr.W3b[4096 + i * 64 + e]);
        const float wvv = bf2f(sm.tr.W3b[8192 + i * 64 + e]);
#pragma unroll
        for (int j = 0; j < 4; ++j) {
          K[j] += qv[j] * wk;
          Q[j] += qv[j] * wq;
          V[j] += qv[j] * wvv;
        }
      }

      float sc[4][4];
#pragma unroll
      for (int j = 0; j < 4; ++j)
#pragma unroll
        for (int k = 0; k < 4; ++k) {
          float p = Q[j] * K[k];
          p += __shfl_xor(p, 1);  p += __shfl_xor(p, 2);  p += __shfl_xor(p, 4);
          p += __shfl_xor(p, 8);  p += __shfl_xor(p, 16); p += __shfl_xor(p, 32);
          sc[j][k] = p * (1.f / 64.f);
        }

      float wsum[4] = {0, 0, 0, 0};
#pragma unroll
      for (int j = 0; j < 4; ++j) {
        float mx = fmaxf(fmaxf(sc[j][0], sc[j][1]), fmaxf(sc[j][2], sc[j][3]));
        float a0 = __expf(sc[j][0] - mx), a1 = __expf(sc[j][1] - mx);
        float a2 = __expf(sc[j][2] - mx), a3 = __expf(sc[j][3] - mx);
        float inv = 1.f / (a0 + a1 + a2 + a3);
        wsum[0] += a0 * inv; wsum[1] += a1 * inv; wsum[2] += a2 * inv; wsum[3] += a3 * inv;
      }

      prev = wsum[0] * V[0] + wsum[1] * V[1] + wsum[2] * V[2] + wsum[3] * V[3];
      __syncthreads();
    }
    treeS[tree * 64 + e] = prev;   // plain store, one writer per tree
  }
}

// ---------------------------------------------------------------------------
// Kernel 1 (grid 512 x 256, pure GEMM — exactly fills 2 blocks/CU, no tail):
//   C = link[b][64 rows] @ relGW  (K=4096, cols=64)
//   BARRIER-FREE per-wave pipeline, BK=128 (512B DRAM runs per row visit).
//   A: 8 global_load_lds/tile into wave-private 2x8KB LDS ring.
//   B: fragment-packed bTf to registers (16 uint4), single-buffered.
//   Steady: LOADB(t) -> STAGEA(t+1) -> vmcnt(8) -> COMPUTE(t).
// ---------------------------------------------------------------------------
__global__ __launch_bounds__(256, 2) void k_main(
    const float* __restrict__ link, const unsigned short* __restrict__ bTf,
    const float* __restrict__ gbias, float* __restrict__ pooled_sum) {
  __shared__ char aLds[4][2][8192];    // 64 KB

  const int t = threadIdx.x;
  const int lane = t & 63;
  const int wid = t >> 6;            // 0..3

  const int gid = blockIdx.x;               // 0..511
  const int b = gid >> 6;                   // batch
  const int rb = gid & 63;                  // 64-row block
  const int rowG0 = rb * 64 + wid * 16;     // this wave's first row
  const int phase = (gid * 4 + wid + b * 9) & 31;   // 32 tiles of 128k
  const int g = lane >> 4;                  // k-group 0..3
  const int r = lane & 15;                  // row/col within fragment
  const uint32_t fr = (uint32_t)((r & 7) << 4);

  const char* linkb = (const char*)(link + ((size_t)b << 24));
  const char* bTfb = (const char*)bTf;
  const int a_r2 = lane >> 5;                       // 0..1
  const uint32_t a_wb = (uint32_t)((lane & 31) * 16);

  char* a0buf = aLds[wid][0];
  char* a1buf = aLds[wid][1];

  f32x4 acc[4];
#pragma unroll
  for (int nt = 0; nt < 4; ++nt) acc[nt] = (f32x4){0.f, 0.f, 0.f, 0.f};
  uint4 bq[16];

#define STAGEA(ab_, tta) do {                                              \
    const size_t ka = (size_t)(tta) * 512;  /* 128k * 4B per row */        \
    _Pragma("unroll")                                                      \
    for (int j = 0; j < 8; ++j) {                                          \
      const int wlrow = 2 * j + a_r2;                                      \
      const uint32_t cb = a_wb ^ ((uint32_t)(wlrow & 7) << 4);             \
      GLOAD_LDS16(linkb + (size_t)(rowG0 + wlrow) * 16384 + ka + cb,       \
                  (ab_) + j * 1024);                                       \
    }                                                                      \
  } while (0)

#define LOADB(tta) do {                                                    \
    const char* bb = bTfb + (size_t)(tta) * 16384 + lane * 16;             \
    _Pragma("unroll")                                                      \
    for (int j = 0; j < 8; ++j) {                                          \
      bq[j]     = *(const uint4*)(bb + j * 1024);                          \
      bq[8 + j] = *(const uint4*)(bb + 8192 + j * 1024);                   \
    }                                                                      \
  } while (0)

#define COMPUTEW(ab_) do {                                                 \
    const char* ar = (ab_) + r * 512;                                      \
    _Pragma("unroll")                                                      \
    for (int kh = 0; kh < 2; ++kh) {                                       \
      _Pragma("unroll")                                                    \
      for (int kc = 0; kc < 2; ++kc) {                                     \
        const uint32_t o0 = ((uint32_t)(kh * 256 + kc * 128 + g * 32)) ^ fr; \
        const f32x4 a0 = *(const f32x4*)(ar + o0);                         \
        const f32x4 a1 = *(const f32x4*)(ar + (o0 ^ 16));                  \
        FragU f;                                                           \
        f.h[0] = __float22bfloat162_rn(float2{a0[0], a0[1]});              \
        f.h[1] = __float22bfloat162_rn(float2{a0[2], a0[3]});              \
        f.h[2] = __float22bfloat162_rn(float2{a1[0], a1[1]});              \
        f.h[3] = __float22bfloat162_rn(float2{a1[2], a1[3]});              \
        _Pragma("unroll")                                                  \
        for (int nt = 0; nt < 4; ++nt) {                                   \
          BU bu; bu.u = bq[kh * 8 + nt * 2 + kc];                          \
          acc[nt] = __builtin_amdgcn_mfma_f32_16x16x32_bf16(f.s, bu.s, acc[nt], 0, 0, 0); \
        }                                                                  \
      }                                                                    \
    }                                                                      \
  } while (0)

  STAGEA(a0buf, phase);                  // tile 0 into buf0
  for (int it2 = 0; it2 < 16; ++it2) {
    const int te = 2 * it2;
    // even tile -> buf0
    LOADB((te + phase) & 31);
    STAGEA(a1buf, (te + 1 + phase) & 31);
    asm volatile("s_waitcnt vmcnt(8)" ::: "memory");   // A(te),B(te) done; A(te+1) in flight
    COMPUTEW(a0buf);
    // odd tile -> buf1
    LOADB((te + 1 + phase) & 31);
    if (it2 < 15) {
      STAGEA(a0buf, (te + 2 + phase) & 31);
      asm volatile("s_waitcnt vmcnt(8)" ::: "memory");
    } else {
      asm volatile("s_waitcnt vmcnt(0)" ::: "memory");
    }
    COMPUTEW(a1buf);
  }

  // ---- epilogue: relu(C + bias) colsum over this wave's 16 rows ----
#pragma unroll
  for (int nt = 0; nt < 4; ++nt) {
    const float gbv = gbias[nt * 16 + r];
    float s = 0.f;
#pragma unroll
    for (int j = 0; j < 4; ++j) s += fmaxf(acc[nt][j] + gbv, 0.f);
    s += __shfl_xor(s, 16);
    s += __shfl_xor(s, 32);
    if (g == 0) atomicAdd(&pooled_sum[b * 64 + nt * 16 + r], s);
  }
}

// ---------------------------------------------------------------------------
// Kernel 2: logits = [pooled_sum/4096 || sum_t treeS] @ fc_w + clip(log(mask))
// grid 128 x 256
// ---------------------------------------------------------------------------
__global__ void k_final(const float* __restrict__ action_mask, const float* __restrict__ fc_w,
                        const float* __restrict__ pooled_sum, const float* __restrict__ treeS,
                        float* __restrict__ out) {
  __shared__ float c[128];
  const int b = blockIdx.x >> 4;
  const int a = ((blockIdx.x & 15) << 8) + threadIdx.x;
  if (threadIdx.x < 128) {
    float v;
    if (threadIdx.x < 64) {
      v = pooled_sum[b * 64 + threadIdx.x] * (1.f / 4096.f);
    } else {
      const float* ts = treeS + (size_t)(b * 8) * 64 + (threadIdx.x - 64);
      v = 0.f;
#pragma unroll
      for (int tt = 0; tt < 8; ++tt) v += ts[tt * 64];
    }
    c[threadIdx.x] = v;
  }
  __syncthreads();
  float acc = 0.f;
  for (int i = 0; i < 128; ++i) acc += c[i] * fc_w[i * 4096 + a];
  const float m = action_mask[b * 4096 + a];
  float lg = __logf(m);
  lg = fminf(fmaxf(lg, -3.4e38f), 3.4e38f);
  out[b * 4096 + a] = lg + acc;
}

// ---------------------------------------------------------------------------
extern "C" void kernel_launch(void* const* d_in, const int* in_sizes, int n_in,
                              void* d_out, int out_size, void* d_ws, size_t ws_size,
                              hipStream_t stream) {
  const float* link = (const float*)d_in[0];
  const float* mask = (const float*)d_in[1];
  const float* col = (const float*)d_in[2];
  const float* rel = (const float*)d_in[3];
  const float* GW = (const float*)d_in[4];
  const float* gb = (const float*)d_in[5];
  const float* Wk = (const float*)d_in[6];
  const float* Wq = (const float*)d_in[7];
  const float* Wv = (const float*)d_in[8];
  const float* fcw = (const float*)d_in[9];
  const int* tids = (const int*)d_in[10];
  const int* lids = (const int*)d_in[11];
  const int* rids = (const int*)d_in[12];
  float* out = (float*)d_out;

  unsigned short* bTf = (unsigned short*)d_ws;              // 512 KB (frag-packed relGW)
  float* pooled_sum = (float*)((char*)d_ws + 512 * 1024);   // 512 floats (zeroed by k_prep)
  float* treeS = (float*)((char*)d_ws + 512 * 1024 + 4096); // 64x64 floats (plain stores)

  hipLaunchKernelGGL(k_prep, dim3(80), dim3(256), 0, stream,
                     rel, GW, bTf, pooled_sum, col, rel, Wk, Wq, Wv, tids, lids, rids, treeS);
  hipLaunchKernelGGL(k_main, dim3(512), dim3(256), 0, stream,
                     link, bTf, gb, pooled_sum);
  hipLaunchKernelGGL(k_final, dim3(128), dim3(256), 0, stream, mask, fcw, pooled_sum, treeS, out);
}

// Round 17
// 158.091 us; speedup vs baseline: 1.3252x; 1.2885x over previous
//
#include <hip/hip_runtime.h>
#include <hip/hip_bf16.h>
#include <stdint.h>

typedef __attribute__((ext_vector_type(8))) short short8;
typedef __attribute__((ext_vector_type(4))) float f32x4;

union FragU { short8 s; __hip_bfloat162 h[4]; };
union BU { uint4 u; short8 s; };

__device__ __forceinline__ unsigned short f2bf(float f) {
  union { float f; unsigned int u; } v; v.f = f;
  unsigned int r = v.u + 0x7fffu + ((v.u >> 16) & 1u);
  return (unsigned short)(r >> 16);
}
__device__ __forceinline__ float bf2f(unsigned short h) {
  union { unsigned int u; float f; } v; v.u = ((unsigned int)h) << 16;
  return v.f;
}

// async global -> LDS, 16B per lane. LDS dest = uniform base + lane*16 (linear).
#define GLOAD_LDS16(gp, lp) \
  __builtin_amdgcn_global_load_lds((const __attribute__((address_space(1))) void*)(gp), \
                                   (__attribute__((address_space(3))) void*)(lp), 16, 0, 0)

// ---------------------------------------------------------------------------
// Kernel 0 (grid 64 x 256): bTf = relGW packed in MFMA-fragment order;
// block 0 zeros the 1024-float accumulator region (pooled_sum + tree_emb).
// ---------------------------------------------------------------------------
__global__ void k_prep(const float* __restrict__ rel, const float* __restrict__ GW,
                       unsigned short* __restrict__ bTf, float* __restrict__ accums) {
  __shared__ float tile[64][65];
  __shared__ float gws[64][64];
  __shared__ float relgw[64][64];
  const int j = blockIdx.x;
  const int t = threadIdx.x;
#pragma unroll
  for (int p = 0; p < 16; ++p) {
    int elem = p * 256 + t;
    int kk = elem >> 6, ee = elem & 63;
    tile[kk][ee] = rel[(j * 64 + kk) * 64 + ee];
    ((float*)gws)[elem] = GW[elem];
  }
  __syncthreads();
  {
    const int e = t >> 2, chunk = t & 3;
    for (int i = 0; i < 16; ++i) {
      float acc = 0.f;
#pragma unroll
      for (int ii = 0; ii < 64; ++ii) acc += tile[chunk * 16 + i][ii] * gws[ii][e];
      relgw[chunk * 16 + i][e] = acc;
    }
  }
  __syncthreads();
#pragma unroll
  for (int m = 0; m < 2; ++m) {
    const int f = t * 2 + m;
    const int nt = f >> 7, kc = (f >> 6) & 1, ln = f & 63;
    const int g = ln >> 4, r = ln & 15;
    union { unsigned short u16[8]; uint4 v; } pk;
#pragma unroll
    for (int s = 0; s < 8; ++s) pk.u16[s] = f2bf(relgw[kc * 32 + g * 8 + s][nt * 16 + r]);
    *(uint4*)(bTf + (size_t)j * 4096 + f * 8) = pk.v;
  }
  if (j == 0) {
    accums[t] = 0.f; accums[t + 256] = 0.f; accums[t + 512] = 0.f; accums[t + 768] = 0.f;
  }
}

// ---------------------------------------------------------------------------
// Fused main kernel, 128-thread blocks (2 waves), 32KB LDS -> 5 blocks/CU:
// 1056 blocks <= 1280 slots => ALL co-resident, zero straggler tail.
//   blocks 0..31     : tree attention (2 trees per block, one per wave)
//   blocks 32..1055  : GEMM  C = link[b][32 rows] @ relGW  (K=4096, cols=64)
//     R12-proven BARRIER-FREE per-wave pipeline, BK=128 (512B DRAM runs):
//     A: 8 global_load_lds/tile into wave-private 2x8KB LDS ring.
//     B: fragment-packed bTf to registers (16 uint4), single-buffered.
//     Steady: LOADB(t) -> STAGEA(t+1) -> vmcnt(8) -> COMPUTE(t).
// ---------------------------------------------------------------------------
__global__ __launch_bounds__(128, 2) void k_main(
    const float* __restrict__ link, const unsigned short* __restrict__ bTf,
    const float* __restrict__ gbias, float* __restrict__ pooled_sum,
    const float* __restrict__ col_table, const float* __restrict__ rel_table,
    const float* __restrict__ Wk, const float* __restrict__ Wq, const float* __restrict__ Wv,
    const int* __restrict__ table_ids, const int* __restrict__ l_ids,
    const int* __restrict__ r_ids, float* __restrict__ tree_emb) {
  __shared__ union {
    struct { char a[2][2][8192]; } g;                                // 32 KB
    struct { unsigned short W3b[3 * 4096]; float qT[2][64][4]; } tr; // 26 KB
  } sm;

  const int t = threadIdx.x;
  const int lane = t & 63;
  const int wid = t >> 6;            // 0..1

  if (blockIdx.x >= 32) {
    // ------------------ GEMM branch (independent wave pipelines) ------------
    const int gid = blockIdx.x - 32;          // 0..1023
    const int b = gid >> 7;                   // batch
    const int rb = gid & 127;                 // 32-row block
    const int rowG0 = rb * 32 + wid * 16;     // this wave's first row
    const int phase = (gid * 2 + wid + b * 9) & 31;   // 32 tiles of 128k
    const int g = lane >> 4;                  // k-group 0..3
    const int r = lane & 15;                  // row/col within fragment
    const uint32_t fr = (uint32_t)((r & 7) << 4);

    const char* linkb = (const char*)(link + ((size_t)b << 24));
    const char* bTfb = (const char*)bTf;
    const int a_r2 = lane >> 5;                       // 0..1
    const uint32_t a_wb = (uint32_t)((lane & 31) * 16);

    char* a0buf = sm.g.a[wid][0];
    char* a1buf = sm.g.a[wid][1];

    f32x4 acc[4];
#pragma unroll
    for (int nt = 0; nt < 4; ++nt) acc[nt] = (f32x4){0.f, 0.f, 0.f, 0.f};
    uint4 bq[16];

#define STAGEA(ab_, tta) do {                                              \
    const size_t ka = (size_t)(tta) * 512;  /* 128k * 4B per row */        \
    _Pragma("unroll")                                                      \
    for (int j = 0; j < 8; ++j) {                                          \
      const int wlrow = 2 * j + a_r2;                                      \
      const uint32_t cb = a_wb ^ ((uint32_t)(wlrow & 7) << 4);             \
      GLOAD_LDS16(linkb + (size_t)(rowG0 + wlrow) * 16384 + ka + cb,       \
                  (ab_) + j * 1024);                                       \
    }                                                                      \
  } while (0)

#define LOADB(tta) do {                                                    \
    const char* bb = bTfb + (size_t)(tta) * 16384 + lane * 16;             \
    _Pragma("unroll")                                                      \
    for (int j = 0; j < 8; ++j) {                                          \
      bq[j]     = *(const uint4*)(bb + j * 1024);                          \
      bq[8 + j] = *(const uint4*)(bb + 8192 + j * 1024);                   \
    }                                                                      \
  } while (0)

#define COMPUTEW(ab_) do {                                                 \
    const char* ar = (ab_) + r * 512;                                      \
    _Pragma("unroll")                                                      \
    for (int kh = 0; kh < 2; ++kh) {                                       \
      _Pragma("unroll")                                                    \
      for (int kc = 0; kc < 2; ++kc) {                                     \
        const uint32_t o0 = ((uint32_t)(kh * 256 + kc * 128 + g * 32)) ^ fr; \
        const f32x4 a0 = *(const f32x4*)(ar + o0);                         \
        const f32x4 a1 = *(const f32x4*)(ar + (o0 ^ 16));                  \
        FragU f;                                                           \
        f.h[0] = __float22bfloat162_rn(float2{a0[0], a0[1]});              \
        f.h[1] = __float22bfloat162_rn(float2{a0[2], a0[3]});              \
        f.h[2] = __float22bfloat162_rn(float2{a1[0], a1[1]});              \
        f.h[3] = __float22bfloat162_rn(float2{a1[2], a1[3]});              \
        _Pragma("unroll")                                                  \
        for (int nt = 0; nt < 4; ++nt) {                                   \
          BU bu; bu.u = bq[kh * 8 + nt * 2 + kc];                          \
          acc[nt] = __builtin_amdgcn_mfma_f32_16x16x32_bf16(f.s, bu.s, acc[nt], 0, 0, 0); \
        }                                                                  \
      }                                                                    \
    }                                                                      \
  } while (0)

    STAGEA(a0buf, phase);                  // tile 0 into buf0
    for (int it2 = 0; it2 < 16; ++it2) {
      const int te = 2 * it2;
      // even tile -> buf0
      LOADB((te + phase) & 31);
      STAGEA(a1buf, (te + 1 + phase) & 31);
      asm volatile("s_waitcnt vmcnt(8)" ::: "memory");   // A(te),B(te) done; A(te+1) in flight
      COMPUTEW(a0buf);
      // odd tile -> buf1
      LOADB((te + 1 + phase) & 31);
      if (it2 < 15) {
        STAGEA(a0buf, (te + 2 + phase) & 31);
        asm volatile("s_waitcnt vmcnt(8)" ::: "memory");
      } else {
        asm volatile("s_waitcnt vmcnt(0)" ::: "memory");
      }
      COMPUTEW(a1buf);
    }

    // ---- epilogue: relu(C + bias) colsum over this wave's 16 rows ----
#pragma unroll
    for (int nt = 0; nt < 4; ++nt) {
      const float gbv = gbias[nt * 16 + r];
      float s = 0.f;
#pragma unroll
      for (int j = 0; j < 4; ++j) s += fmaxf(acc[nt][j] + gbv, 0.f);
      s += __shfl_xor(s, 16);
      s += __shfl_xor(s, 32);
      if (g == 0) atomicAdd(&pooled_sum[b * 64 + nt * 16 + r], s);
    }
  } else {
    // ------------------------- tree branch (2 trees/block) ------------------
    const int e = lane;
    for (int i = t; i < 3 * 4096; i += 128) {
      float v;
      if (i < 4096) v = Wk[i];
      else if (i < 8192) v = Wq[i - 4096];
      else v = Wv[i - 8192];
      sm.tr.W3b[i] = f2bf(v);
    }
    __syncthreads();

    const int tree = blockIdx.x * 2 + wid;   // 0..63
    const int b = tree >> 3;
    const int* tid = table_ids + tree * 17;
    const int* lid = l_ids + tree * 32;
    const int* rid = r_ids + tree * 32;

    float prev = rel_table[tid[0] * 64 + e];

    for (int d = 0; d < 16; ++d) {
      const int l0 = lid[d * 2], l1 = lid[d * 2 + 1];
      const int r0 = rid[d * 2], r1 = rid[d * 2 + 1];
      const float lce = 0.5f * (col_table[l0 * 64 + e] + col_table[l1 * 64 + e]);
      const float rce = 0.5f * (col_table[r0 * 64 + e] + col_table[r1 * 64 + e]);
      const float rte = rel_table[tid[1 + d] * 64 + e];
      float4 qv0; qv0.x = prev; qv0.y = lce; qv0.z = rce; qv0.w = rte;
      *(float4*)&sm.tr.qT[wid][e][0] = qv0;
      __syncthreads();

      float K[4] = {0, 0, 0, 0}, Q[4] = {0, 0, 0, 0}, V[4] = {0, 0, 0, 0};
#pragma unroll 8
      for (int i = 0; i < 64; ++i) {
        const f32x4 qv = *(const f32x4*)&sm.tr.qT[wid][i][0];
        const float wk = bf2f(sm.tr.W3b[i * 64 + e]);
        const float wq = bf2f(sm.tr.W3b[4096 + i * 64 + e]);
        const float wvv = bf2f(sm.tr.W3b[8192 + i * 64 + e]);
#pragma unroll
        for (int j = 0; j < 4; ++j) {
          K[j] += qv[j] * wk;
          Q[j] += qv[j] * wq;
          V[j] += qv[j] * wvv;
        }
      }

      float sc[4][4];
#pragma unroll
      for (int j = 0; j < 4; ++j)
#pragma unroll
        for (int k = 0; k < 4; ++k) {
          float p = Q[j] * K[k];
          p += __shfl_xor(p, 1);  p += __shfl_xor(p, 2);  p += __shfl_xor(p, 4);
          p += __shfl_xor(p, 8);  p += __shfl_xor(p, 16); p += __shfl_xor(p, 32);
          sc[j][k] = p * (1.f / 64.f);
        }

      float wsum[4] = {0, 0, 0, 0};
#pragma unroll
      for (int j = 0; j < 4; ++j) {
        float mx = fmaxf(fmaxf(sc[j][0], sc[j][1]), fmaxf(sc[j][2], sc[j][3]));
        float a0 = __expf(sc[j][0] - mx), a1 = __expf(sc[j][1] - mx);
        float a2 = __expf(sc[j][2] - mx), a3 = __expf(sc[j][3] - mx);
        float inv = 1.f / (a0 + a1 + a2 + a3);
        wsum[0] += a0 * inv; wsum[1] += a1 * inv; wsum[2] += a2 * inv; wsum[3] += a3 * inv;
      }

      prev = wsum[0] * V[0] + wsum[1] * V[1] + wsum[2] * V[2] + wsum[3] * V[3];
      __syncthreads();
    }
    atomicAdd(&tree_emb[b * 64 + e], prev);
  }
}

// ---------------------------------------------------------------------------
// Kernel 2: logits = [pooled_sum/4096 || tree_emb] @ fc_w  + clip(log(mask))
// grid 128 x 256
// ---------------------------------------------------------------------------
__global__ void k_final(const float* __restrict__ action_mask, const float* __restrict__ fc_w,
                        const float* __restrict__ pooled_sum, const float* __restrict__ tree_emb,
                        float* __restrict__ out) {
  __shared__ float c[128];
  const int b = blockIdx.x >> 4;
  const int a = ((blockIdx.x & 15) << 8) + threadIdx.x;
  if (threadIdx.x < 128) {
    c[threadIdx.x] = (threadIdx.x < 64) ? pooled_sum[b * 64 + threadIdx.x] * (1.f / 4096.f)
                                        : tree_emb[b * 64 + threadIdx.x - 64];
  }
  __syncthreads();
  float acc = 0.f;
  for (int i = 0; i < 128; ++i) acc += c[i] * fc_w[i * 4096 + a];
  const float m = action_mask[b * 4096 + a];
  float lg = __logf(m);
  lg = fminf(fmaxf(lg, -3.4e38f), 3.4e38f);
  out[b * 4096 + a] = lg + acc;
}

// ---------------------------------------------------------------------------
extern "C" void kernel_launch(void* const* d_in, const int* in_sizes, int n_in,
                              void* d_out, int out_size, void* d_ws, size_t ws_size,
                              hipStream_t stream) {
  const float* link = (const float*)d_in[0];
  const float* mask = (const float*)d_in[1];
  const float* col = (const float*)d_in[2];
  const float* rel = (const float*)d_in[3];
  const float* GW = (const float*)d_in[4];
  const float* gb = (const float*)d_in[5];
  const float* Wk = (const float*)d_in[6];
  const float* Wq = (const float*)d_in[7];
  const float* Wv = (const float*)d_in[8];
  const float* fcw = (const float*)d_in[9];
  const int* tids = (const int*)d_in[10];
  const int* lids = (const int*)d_in[11];
  const int* rids = (const int*)d_in[12];
  float* out = (float*)d_out;

  unsigned short* bTf = (unsigned short*)d_ws;              // 512 KB (frag-packed relGW)
  float* accums = (float*)((char*)d_ws + 512 * 1024);       // 1024 floats
  float* pooled_sum = accums;                               // [8][64]
  float* tree = accums + 512;                               // [8][64]

  hipLaunchKernelGGL(k_prep, dim3(64), dim3(256), 0, stream, rel, GW, bTf, accums);
  hipLaunchKernelGGL(k_main, dim3(1056), dim3(128), 0, stream,
                     link, bTf, gb, pooled_sum,
                     col, rel, Wk, Wq, Wv, tids, lids, rids, tree);
  hipLaunchKernelGGL(k_final, dim3(128), dim3(256), 0, stream, mask, fcw, pooled_sum, tree, out);
}

// Round 18
// 131.651 us; speedup vs baseline: 1.5913x; 1.2008x over previous
//
#include <hip/hip_runtime.h>
#include <hip/hip_bf16.h>
#include <stdint.h>

typedef __attribute__((ext_vector_type(8))) short short8;
typedef __attribute__((ext_vector_type(4))) float f32x4;

union FragU { short8 s; __hip_bfloat162 h[4]; };
union BU { uint4 u; short8 s; };

__device__ __forceinline__ unsigned short f2bf(float f) {
  union { float f; unsigned int u; } v; v.f = f;
  unsigned int r = v.u + 0x7fffu + ((v.u >> 16) & 1u);
  return (unsigned short)(r >> 16);
}
__device__ __forceinline__ float bf2f(unsigned short h) {
  union { unsigned int u; float f; } v; v.u = ((unsigned int)h) << 16;
  return v.f;
}

// async global -> LDS, 16B per lane. LDS dest = uniform base + lane*16 (linear).
// aux: gfx950 CPol — 0 = default, 2 = NT (evict-first; for zero-reuse streams).
#define GLOAD_LDS16(gp, lp) \
  __builtin_amdgcn_global_load_lds((const __attribute__((address_space(1))) void*)(gp), \
                                   (__attribute__((address_space(3))) void*)(lp), 16, 0, 0)
#define GLOAD_LDS16_NT(gp, lp) \
  __builtin_amdgcn_global_load_lds((const __attribute__((address_space(1))) void*)(gp), \
                                   (__attribute__((address_space(3))) void*)(lp), 16, 0, 2)

// ---------------------------------------------------------------------------
// Kernel 0 (grid 64 x 256): bTf = relGW (= rel @ GW) packed in MFMA-fragment
// order per 64-k tile; block 0 zeros the accumulator region.
// ---------------------------------------------------------------------------
__global__ void k_prep(const float* __restrict__ rel, const float* __restrict__ GW,
                       unsigned short* __restrict__ bTf, float* __restrict__ accums) {
  __shared__ float tile[64][65];
  __shared__ float gws[64][64];
  __shared__ float relgw[64][64];
  const int j = blockIdx.x;
  const int t = threadIdx.x;
#pragma unroll
  for (int p = 0; p < 16; ++p) {
    int elem = p * 256 + t;
    int kk = elem >> 6, ee = elem & 63;
    tile[kk][ee] = rel[(j * 64 + kk) * 64 + ee];
    ((float*)gws)[elem] = GW[elem];
  }
  __syncthreads();
  {
    const int e = t >> 2, chunk = t & 3;
    for (int i = 0; i < 16; ++i) {
      float acc = 0.f;
#pragma unroll
      for (int ii = 0; ii < 64; ++ii) acc += tile[chunk * 16 + i][ii] * gws[ii][e];
      relgw[chunk * 16 + i][e] = acc;
    }
  }
  __syncthreads();
#pragma unroll
  for (int m = 0; m < 2; ++m) {
    const int f = t * 2 + m;
    const int nt = f >> 7, kc = (f >> 6) & 1, ln = f & 63;
    const int g = ln >> 4, r = ln & 15;
    union { unsigned short u16[8]; uint4 v; } pk;
#pragma unroll
    for (int s = 0; s < 8; ++s) pk.u16[s] = f2bf(relgw[kc * 32 + g * 8 + s][nt * 16 + r]);
    *(uint4*)(bTf + (size_t)j * 4096 + f * 8) = pk.v;
  }
  if (j == 0) {
    accums[t] = 0.f; accums[t + 256] = 0.f; accums[t + 512] = 0.f; accums[t + 768] = 0.f;
  }
}

// ---------------------------------------------------------------------------
// Fused main kernel, 256-thread blocks (R14 structure, proven 142.9us).
//   blocks 0..15    : tree attention (4 trees per block, one per wave)
//   blocks 16..527  : GEMM  C = link[b][64 rows] @ relGW  (K=4096, cols=64)
//     BARRIER-FREE per-wave pipeline, BK=128 (512B DRAM runs per row visit).
//     A: 8 global_load_lds/tile (NT cache policy — zero reuse, keep L2 for B)
//        into wave-private 2x8KB LDS ring.
//     B: fragment-packed bTf to registers (16 uint4), single-buffered.
//     Steady: LOADB(t) -> STAGEA(t+1) -> vmcnt(8) -> COMPUTE(t).
// ---------------------------------------------------------------------------
__global__ __launch_bounds__(256, 2) void k_main(
    const float* __restrict__ link, const unsigned short* __restrict__ bTf,
    const float* __restrict__ gbias, float* __restrict__ pooled_sum,
    const float* __restrict__ col_table, const float* __restrict__ rel_table,
    const float* __restrict__ Wk, const float* __restrict__ Wq, const float* __restrict__ Wv,
    const int* __restrict__ table_ids, const int* __restrict__ l_ids,
    const int* __restrict__ r_ids, float* __restrict__ tree_emb) {
  __shared__ union {
    struct { char a[4][2][8192]; } g;                                // 64 KB
    struct { unsigned short W3b[3 * 4096]; float qT[4][64][4]; } tr; // 28 KB
  } sm;

  const int t = threadIdx.x;
  const int lane = t & 63;
  const int wid = t >> 6;            // 0..3

  if (blockIdx.x >= 16) {
    // ------------------ GEMM branch (independent wave pipelines) ------------
    const int gid = blockIdx.x - 16;          // 0..511
    const int b = gid >> 6;                   // batch
    const int rb = gid & 63;                  // 64-row block
    const int rowG0 = rb * 64 + wid * 16;     // this wave's first row
    const int phase = (gid * 4 + wid + b * 9) & 31;   // 32 tiles of 128k
    const int g = lane >> 4;                  // k-group 0..3
    const int r = lane & 15;                  // row/col within fragment
    const uint32_t fr = (uint32_t)((r & 7) << 4);

    const char* linkb = (const char*)(link + ((size_t)b << 24));
    const char* bTfb = (const char*)bTf;
    const int a_r2 = lane >> 5;                       // 0..1
    const uint32_t a_wb = (uint32_t)((lane & 31) * 16);

    char* a0buf = sm.g.a[wid][0];
    char* a1buf = sm.g.a[wid][1];

    f32x4 acc[4];
#pragma unroll
    for (int nt = 0; nt < 4; ++nt) acc[nt] = (f32x4){0.f, 0.f, 0.f, 0.f};
    uint4 bq[16];

#define STAGEA(ab_, tta) do {                                              \
    const size_t ka = (size_t)(tta) * 512;  /* 128k * 4B per row */        \
    _Pragma("unroll")                                                      \
    for (int j = 0; j < 8; ++j) {                                          \
      const int wlrow = 2 * j + a_r2;                                      \
      const uint32_t cb = a_wb ^ ((uint32_t)(wlrow & 7) << 4);             \
      GLOAD_LDS16_NT(linkb + (size_t)(rowG0 + wlrow) * 16384 + ka + cb,    \
                     (ab_) + j * 1024);                                    \
    }                                                                      \
  } while (0)

#define LOADB(tta) do {                                                    \
    const char* bb = bTfb + (size_t)(tta) * 16384 + lane * 16;             \
    _Pragma("unroll")                                                      \
    for (int j = 0; j < 8; ++j) {                                          \
      bq[j]     = *(const uint4*)(bb + j * 1024);                          \
      bq[8 + j] = *(const uint4*)(bb + 8192 + j * 1024);                   \
    }                                                                      \
  } while (0)

#define COMPUTEW(ab_) do {                                                 \
    const char* ar = (ab_) + r * 512;                                      \
    _Pragma("unroll")                                                      \
    for (int kh = 0; kh < 2; ++kh) {                                       \
      _Pragma("unroll")                                                    \
      for (int kc = 0; kc < 2; ++kc) {                                     \
        const uint32_t o0 = ((uint32_t)(kh * 256 + kc * 128 + g * 32)) ^ fr; \
        const f32x4 a0 = *(const f32x4*)(ar + o0);                         \
        const f32x4 a1 = *(const f32x4*)(ar + (o0 ^ 16));                  \
        FragU f;                                                           \
        f.h[0] = __float22bfloat162_rn(float2{a0[0], a0[1]});              \
        f.h[1] = __float22bfloat162_rn(float2{a0[2], a0[3]});              \
        f.h[2] = __float22bfloat162_rn(float2{a1[0], a1[1]});              \
        f.h[3] = __float22bfloat162_rn(float2{a1[2], a1[3]});              \
        _Pragma("unroll")                                                  \
        for (int nt = 0; nt < 4; ++nt) {                                   \
          BU bu; bu.u = bq[kh * 8 + nt * 2 + kc];                          \
          acc[nt] = __builtin_amdgcn_mfma_f32_16x16x32_bf16(f.s, bu.s, acc[nt], 0, 0, 0); \
        }                                                                  \
      }                                                                    \
    }                                                                      \
  } while (0)

    STAGEA(a0buf, phase);                  // tile 0 into buf0
    for (int it2 = 0; it2 < 16; ++it2) {
      const int te = 2 * it2;
      // even tile -> buf0
      LOADB((te + phase) & 31);
      STAGEA(a1buf, (te + 1 + phase) & 31);
      asm volatile("s_waitcnt vmcnt(8)" ::: "memory");   // A(te),B(te) done; A(te+1) in flight
      COMPUTEW(a0buf);
      // odd tile -> buf1
      LOADB((te + 1 + phase) & 31);
      if (it2 < 15) {
        STAGEA(a0buf, (te + 2 + phase) & 31);
        asm volatile("s_waitcnt vmcnt(8)" ::: "memory");
      } else {
        asm volatile("s_waitcnt vmcnt(0)" ::: "memory");
      }
      COMPUTEW(a1buf);
    }

    // ---- epilogue: relu(C + bias) colsum over this wave's 16 rows ----
#pragma unroll
    for (int nt = 0; nt < 4; ++nt) {
      const float gbv = gbias[nt * 16 + r];
      float s = 0.f;
#pragma unroll
      for (int j = 0; j < 4; ++j) s += fmaxf(acc[nt][j] + gbv, 0.f);
      s += __shfl_xor(s, 16);
      s += __shfl_xor(s, 32);
      if (g == 0) atomicAdd(&pooled_sum[b * 64 + nt * 16 + r], s);
    }
  } else {
    // ------------------------- tree branch ----------------------------------
    const int e = lane;
    for (int i = t; i < 3 * 4096; i += 256) {
      float v;
      if (i < 4096) v = Wk[i];
      else if (i < 8192) v = Wq[i - 4096];
      else v = Wv[i - 8192];
      sm.tr.W3b[i] = f2bf(v);
    }
    __syncthreads();

    const int tree = blockIdx.x * 4 + wid;   // 0..63
    const int b = tree >> 3;
    const int* tid = table_ids + tree * 17;
    const int* lid = l_ids + tree * 32;
    const int* rid = r_ids + tree * 32;

    float prev = rel_table[tid[0] * 64 + e];

    for (int d = 0; d < 16; ++d) {
      const int l0 = lid[d * 2], l1 = lid[d * 2 + 1];
      const int r0 = rid[d * 2], r1 = rid[d * 2 + 1];
      const float lce = 0.5f * (col_table[l0 * 64 + e] + col_table[l1 * 64 + e]);
      const float rce = 0.5f * (col_table[r0 * 64 + e] + col_table[r1 * 64 + e]);
      const float rte = rel_table[tid[1 + d] * 64 + e];
      float4 qv0; qv0.x = prev; qv0.y = lce; qv0.z = rce; qv0.w = rte;
      *(float4*)&sm.tr.qT[wid][e][0] = qv0;
      __syncthreads();

      float K[4] = {0, 0, 0, 0}, Q[4] = {0, 0, 0, 0}, V[4] = {0, 0, 0, 0};
#pragma unroll 8
      for (int i = 0; i < 64; ++i) {
        const f32x4 qv = *(const f32x4*)&sm.tr.qT[wid][i][0];
        const float wk = bf2f(sm.tr.W3b[i * 64 + e]);
        const float wq = bf2f(sm.tr.W3b[4096 + i * 64 + e]);
        const float wvv = bf2f(sm.tr.W3b[8192 + i * 64 + e]);
#pragma unroll
        for (int j = 0; j < 4; ++j) {
          K[j] += qv[j] * wk;
          Q[j] += qv[j] * wq;
          V[j] += qv[j] * wvv;
        }
      }

      float sc[4][4];
#pragma unroll
      for (int j = 0; j < 4; ++j)
#pragma unroll
        for (int k = 0; k < 4; ++k) {
          float p = Q[j] * K[k];
          p += __shfl_xor(p, 1);  p += __shfl_xor(p, 2);  p += __shfl_xor(p, 4);
          p += __shfl_xor(p, 8);  p += __shfl_xor(p, 16); p += __shfl_xor(p, 32);
          sc[j][k] = p * (1.f / 64.f);
        }

      float wsum[4] = {0, 0, 0, 0};
#pragma unroll
      for (int j = 0; j < 4; ++j) {
        float mx = fmaxf(fmaxf(sc[j][0], sc[j][1]), fmaxf(sc[j][2], sc[j][3]));
        float a0 = __expf(sc[j][0] - mx), a1 = __expf(sc[j][1] - mx);
        float a2 = __expf(sc[j][2] - mx), a3 = __expf(sc[j][3] - mx);
        float inv = 1.f / (a0 + a1 + a2 + a3);
        wsum[0] += a0 * inv; wsum[1] += a1 * inv; wsum[2] += a2 * inv; wsum[3] += a3 * inv;
      }

      prev = wsum[0] * V[0] + wsum[1] * V[1] + wsum[2] * V[2] + wsum[3] * V[3];
      __syncthreads();
    }
    atomicAdd(&tree_emb[b * 64 + e], prev);
  }
}

// ---------------------------------------------------------------------------
// Kernel 2: logits = [pooled_sum/4096 || tree_emb] @ fc_w  + clip(log(mask))
// grid 128 x 256
// ---------------------------------------------------------------------------
__global__ void k_final(const float* __restrict__ action_mask, const float* __restrict__ fc_w,
                        const float* __restrict__ pooled_sum, const float* __restrict__ tree_emb,
                        float* __restrict__ out) {
  __shared__ float c[128];
  const int b = blockIdx.x >> 4;
  const int a = ((blockIdx.x & 15) << 8) + threadIdx.x;
  if (threadIdx.x < 128) {
    c[threadIdx.x] = (threadIdx.x < 64) ? pooled_sum[b * 64 + threadIdx.x] * (1.f / 4096.f)
                                        : tree_emb[b * 64 + threadIdx.x - 64];
  }
  __syncthreads();
  float acc = 0.f;
  for (int i = 0; i < 128; ++i) acc += c[i] * fc_w[i * 4096 + a];
  const float m = action_mask[b * 4096 + a];
  float lg = __logf(m);
  lg = fminf(fmaxf(lg, -3.4e38f), 3.4e38f);
  out[b * 4096 + a] = lg + acc;
}

// ---------------------------------------------------------------------------
extern "C" void kernel_launch(void* const* d_in, const int* in_sizes, int n_in,
                              void* d_out, int out_size, void* d_ws, size_t ws_size,
                              hipStream_t stream) {
  const float* link = (const float*)d_in[0];
  const float* mask = (const float*)d_in[1];
  const float* col = (const float*)d_in[2];
  const float* rel = (const float*)d_in[3];
  const float* GW = (const float*)d_in[4];
  const float* gb = (const float*)d_in[5];
  const float* Wk = (const float*)d_in[6];
  const float* Wq = (const float*)d_in[7];
  const float* Wv = (const float*)d_in[8];
  const float* fcw = (const float*)d_in[9];
  const int* tids = (const int*)d_in[10];
  const int* lids = (const int*)d_in[11];
  const int* rids = (const int*)d_in[12];
  float* out = (float*)d_out;

  unsigned short* bTf = (unsigned short*)d_ws;              // 512 KB (frag-packed relGW)
  float* accums = (float*)((char*)d_ws + 512 * 1024);       // 1024 floats
  float* pooled_sum = accums;                               // [8][64]
  float* tree = accums + 512;                               // [8][64]

  hipLaunchKernelGGL(k_prep, dim3(64), dim3(256), 0, stream, rel, GW, bTf, accums);
  hipLaunchKernelGGL(k_main, dim3(528), dim3(256), 0, stream,
                     link, bTf, gb, pooled_sum,
                     col, rel, Wk, Wq, Wv, tids, lids, rids, tree);
  hipLaunchKernelGGL(k_final, dim3(128), dim3(256), 0, stream, mask, fcw, pooled_sum, tree, out);
}

// Round 19
// 130.310 us; speedup vs baseline: 1.6077x; 1.0103x over previous
//
#include <hip/hip_runtime.h>
#include <hip/hip_bf16.h>
#include <stdint.h>

typedef __attribute__((ext_vector_type(8))) short short8;
typedef __attribute__((ext_vector_type(4))) float f32x4;

union FragU { short8 s; __hip_bfloat162 h[4]; };
union BU { uint4 u; short8 s; };

__device__ __forceinline__ unsigned short f2bf(float f) {
  union { float f; unsigned int u; } v; v.f = f;
  unsigned int r = v.u + 0x7fffu + ((v.u >> 16) & 1u);
  return (unsigned short)(r >> 16);
}
__device__ __forceinline__ float bf2f(unsigned short h) {
  union { unsigned int u; float f; } v; v.u = ((unsigned int)h) << 16;
  return v.f;
}

// async global -> LDS, 16B per lane. LDS dest = uniform base + lane*16 (linear).
// aux: gfx950 CPol — 0 = default, 2 = NT (evict-first; for zero-reuse streams).
#define GLOAD_LDS16_NT(gp, lp) \
  __builtin_amdgcn_global_load_lds((const __attribute__((address_space(1))) void*)(gp), \
                                   (__attribute__((address_space(3))) void*)(lp), 16, 0, 2)

// ---------------------------------------------------------------------------
// Kernel 0 (grid 64 x 256): bTf = relGW (= rel @ GW) packed in MFMA-fragment
// order per 64-k tile; block 0 zeros the accumulator region.
// ---------------------------------------------------------------------------
__global__ void k_prep(const float* __restrict__ rel, const float* __restrict__ GW,
                       unsigned short* __restrict__ bTf, float* __restrict__ accums) {
  __shared__ float tile[64][65];
  __shared__ float gws[64][64];
  __shared__ float relgw[64][64];
  const int j = blockIdx.x;
  const int t = threadIdx.x;
#pragma unroll
  for (int p = 0; p < 16; ++p) {
    int elem = p * 256 + t;
    int kk = elem >> 6, ee = elem & 63;
    tile[kk][ee] = rel[(j * 64 + kk) * 64 + ee];
    ((float*)gws)[elem] = GW[elem];
  }
  __syncthreads();
  {
    const int e = t >> 2, chunk = t & 3;
    for (int i = 0; i < 16; ++i) {
      float acc = 0.f;
#pragma unroll
      for (int ii = 0; ii < 64; ++ii) acc += tile[chunk * 16 + i][ii] * gws[ii][e];
      relgw[chunk * 16 + i][e] = acc;
    }
  }
  __syncthreads();
#pragma unroll
  for (int m = 0; m < 2; ++m) {
    const int f = t * 2 + m;
    const int nt = f >> 7, kc = (f >> 6) & 1, ln = f & 63;
    const int g = ln >> 4, r = ln & 15;
    union { unsigned short u16[8]; uint4 v; } pk;
#pragma unroll
    for (int s = 0; s < 8; ++s) pk.u16[s] = f2bf(relgw[kc * 32 + g * 8 + s][nt * 16 + r]);
    *(uint4*)(bTf + (size_t)j * 4096 + f * 8) = pk.v;
  }
  if (j == 0) {
    accums[t] = 0.f; accums[t + 256] = 0.f; accums[t + 512] = 0.f; accums[t + 768] = 0.f;
  }
}

// ---------------------------------------------------------------------------
// Fused main kernel, 256-thread blocks (R18 champion + pair-burst A staging).
//   blocks 0..15    : tree attention (4 trees per block, one per wave)
//   blocks 16..527  : GEMM  C = link[b][64 rows] @ relGW  (K=4096, cols=64)
//     BARRIER-FREE per-wave pipeline. A staged in TILE-PAIR bursts:
//     STAGEA(a0,t);STAGEA(a1,t+1) back-to-back so each link-row's two 512B
//     strips issue ~8 instrs apart (one DRAM row activation serves 1KB).
//     B double-set in registers (bq0/bq1), loaded a full pair ahead so the
//     A bursts are always the NEWEST vmcnt entries (no drain).
//     Per pair: vmcnt(8)->COMP(a0)->LOADB(bq0,t+2)->vmcnt(16)->COMP(a1)
//               ->LOADB(bq1,t+3)->STAGEA(a0,t+2)+STAGEA(a1,t+3).
// ---------------------------------------------------------------------------
__global__ __launch_bounds__(256, 2) void k_main(
    const float* __restrict__ link, const unsigned short* __restrict__ bTf,
    const float* __restrict__ gbias, float* __restrict__ pooled_sum,
    const float* __restrict__ col_table, const float* __restrict__ rel_table,
    const float* __restrict__ Wk, const float* __restrict__ Wq, const float* __restrict__ Wv,
    const int* __restrict__ table_ids, const int* __restrict__ l_ids,
    const int* __restrict__ r_ids, float* __restrict__ tree_emb) {
  __shared__ union {
    struct { char a[4][2][8192]; } g;                                // 64 KB
    struct { unsigned short W3b[3 * 4096]; float qT[4][64][4]; } tr; // 28 KB
  } sm;

  const int t = threadIdx.x;
  const int lane = t & 63;
  const int wid = t >> 6;            // 0..3

  if (blockIdx.x >= 16) {
    // ------------------ GEMM branch (independent wave pipelines) ------------
    const int gid = blockIdx.x - 16;          // 0..511
    const int b = gid >> 6;                   // batch
    const int rb = gid & 63;                  // 64-row block
    const int rowG0 = rb * 64 + wid * 16;     // this wave's first row
    const int phase = (gid * 4 + wid + b * 9) & 31;   // 32 tiles of 128k
    const int g = lane >> 4;                  // k-group 0..3
    const int r = lane & 15;                  // row/col within fragment
    const uint32_t fr = (uint32_t)((r & 7) << 4);

    const char* linkb = (const char*)(link + ((size_t)b << 24));
    const char* bTfb = (const char*)bTf;
    const int a_r2 = lane >> 5;                       // 0..1
    const uint32_t a_wb = (uint32_t)((lane & 31) * 16);

    char* a0buf = sm.g.a[wid][0];
    char* a1buf = sm.g.a[wid][1];

    f32x4 acc[4];
#pragma unroll
    for (int nt = 0; nt < 4; ++nt) acc[nt] = (f32x4){0.f, 0.f, 0.f, 0.f};
    uint4 bq0[16], bq1[16];

#define STAGEA(ab_, tta) do {                                              \
    const size_t ka = (size_t)(tta) * 512;  /* 128k * 4B per row */        \
    _Pragma("unroll")                                                      \
    for (int j = 0; j < 8; ++j) {                                          \
      const int wlrow = 2 * j + a_r2;                                      \
      const uint32_t cb = a_wb ^ ((uint32_t)(wlrow & 7) << 4);             \
      GLOAD_LDS16_NT(linkb + (size_t)(rowG0 + wlrow) * 16384 + ka + cb,    \
                     (ab_) + j * 1024);                                    \
    }                                                                      \
  } while (0)

#define LOADB(bq_, tta) do {                                               \
    const char* bb = bTfb + (size_t)(tta) * 16384 + lane * 16;             \
    _Pragma("unroll")                                                      \
    for (int j = 0; j < 8; ++j) {                                          \
      bq_[j]     = *(const uint4*)(bb + j * 1024);                         \
      bq_[8 + j] = *(const uint4*)(bb + 8192 + j * 1024);                  \
    }                                                                      \
  } while (0)

#define COMPUTEW(ab_, bq_) do {                                            \
    const char* ar = (ab_) + r * 512;                                      \
    _Pragma("unroll")                                                      \
    for (int kh = 0; kh < 2; ++kh) {                                       \
      _Pragma("unroll")                                                    \
      for (int kc = 0; kc < 2; ++kc) {                                     \
        const uint32_t o0 = ((uint32_t)(kh * 256 + kc * 128 + g * 32)) ^ fr; \
        const f32x4 a0 = *(const f32x4*)(ar + o0);                         \
        const f32x4 a1 = *(const f32x4*)(ar + (o0 ^ 16));                  \
        FragU f;                                                           \
        f.h[0] = __float22bfloat162_rn(float2{a0[0], a0[1]});              \
        f.h[1] = __float22bfloat162_rn(float2{a0[2], a0[3]});              \
        f.h[2] = __float22bfloat162_rn(float2{a1[0], a1[1]});              \
        f.h[3] = __float22bfloat162_rn(float2{a1[2], a1[3]});              \
        _Pragma("unroll")                                                  \
        for (int nt = 0; nt < 4; ++nt) {                                   \
          BU bu; bu.u = bq_[kh * 8 + nt * 2 + kc];                         \
          acc[nt] = __builtin_amdgcn_mfma_f32_16x16x32_bf16(f.s, bu.s, acc[nt], 0, 0, 0); \
        }                                                                  \
      }                                                                    \
    }                                                                      \
  } while (0)

    // prologue: B for pair 0, then the adjacent A pair-burst
    LOADB(bq0, phase);
    LOADB(bq1, (phase + 1) & 31);
    STAGEA(a0buf, phase);
    STAGEA(a1buf, (phase + 1) & 31);

    for (int it2 = 0; it2 < 16; ++it2) {
      const int te = 2 * it2;
      // outstanding: B0(16),B1(16),A-lo(8),A-hi(8) -> keep newest 8 (A-hi)
      asm volatile("s_waitcnt vmcnt(8)" ::: "memory");
      COMPUTEW(a0buf, bq0);
      if (it2 < 15) {
        LOADB(bq0, (te + 2 + phase) & 31);
        // outstanding: A-hi(8) + B0new(16) -> keep newest 16 (B0new)
        asm volatile("s_waitcnt vmcnt(16)" ::: "memory");
      } else {
        asm volatile("s_waitcnt vmcnt(0)" ::: "memory");
      }
      COMPUTEW(a1buf, bq1);
      if (it2 < 15) {
        LOADB(bq1, (te + 3 + phase) & 31);
        STAGEA(a0buf, (te + 2 + phase) & 31);   // adjacent pair-burst:
        STAGEA(a1buf, (te + 3 + phase) & 31);   // row strips 8 instrs apart
      }
    }

    // ---- epilogue: relu(C + bias) colsum over this wave's 16 rows ----
#pragma unroll
    for (int nt = 0; nt < 4; ++nt) {
      const float gbv = gbias[nt * 16 + r];
      float s = 0.f;
#pragma unroll
      for (int j = 0; j < 4; ++j) s += fmaxf(acc[nt][j] + gbv, 0.f);
      s += __shfl_xor(s, 16);
      s += __shfl_xor(s, 32);
      if (g == 0) atomicAdd(&pooled_sum[b * 64 + nt * 16 + r], s);
    }
  } else {
    // ------------------------- tree branch ----------------------------------
    const int e = lane;
    for (int i = t; i < 3 * 4096; i += 256) {
      float v;
      if (i < 4096) v = Wk[i];
      else if (i < 8192) v = Wq[i - 4096];
      else v = Wv[i - 8192];
      sm.tr.W3b[i] = f2bf(v);
    }
    __syncthreads();

    const int tree = blockIdx.x * 4 + wid;   // 0..63
    const int b = tree >> 3;
    const int* tid = table_ids + tree * 17;
    const int* lid = l_ids + tree * 32;
    const int* rid = r_ids + tree * 32;

    float prev = rel_table[tid[0] * 64 + e];

    for (int d = 0; d < 16; ++d) {
      const int l0 = lid[d * 2], l1 = lid[d * 2 + 1];
      const int r0 = rid[d * 2], r1 = rid[d * 2 + 1];
      const float lce = 0.5f * (col_table[l0 * 64 + e] + col_table[l1 * 64 + e]);
      const float rce = 0.5f * (col_table[r0 * 64 + e] + col_table[r1 * 64 + e]);
      const float rte = rel_table[tid[1 + d] * 64 + e];
      float4 qv0; qv0.x = prev; qv0.y = lce; qv0.z = rce; qv0.w = rte;
      *(float4*)&sm.tr.qT[wid][e][0] = qv0;
      __syncthreads();

      float K[4] = {0, 0, 0, 0}, Q[4] = {0, 0, 0, 0}, V[4] = {0, 0, 0, 0};
#pragma unroll 8
      for (int i = 0; i < 64; ++i) {
        const f32x4 qv = *(const f32x4*)&sm.tr.qT[wid][i][0];
        const float wk = bf2f(sm.tr.W3b[i * 64 + e]);
        const float wq = bf2f(sm.tr.W3b[4096 + i * 64 + e]);
        const float wvv = bf2f(sm.tr.W3b[8192 + i * 64 + e]);
#pragma unroll
        for (int j = 0; j < 4; ++j) {
          K[j] += qv[j] * wk;
          Q[j] += qv[j] * wq;
          V[j] += qv[j] * wvv;
        }
      }

      float sc[4][4];
#pragma unroll
      for (int j = 0; j < 4; ++j)
#pragma unroll
        for (int k = 0; k < 4; ++k) {
          float p = Q[j] * K[k];
          p += __shfl_xor(p, 1);  p += __shfl_xor(p, 2);  p += __shfl_xor(p, 4);
          p += __shfl_xor(p, 8);  p += __shfl_xor(p, 16); p += __shfl_xor(p, 32);
          sc[j][k] = p * (1.f / 64.f);
        }

      float wsum[4] = {0, 0, 0, 0};
#pragma unroll
      for (int j = 0; j < 4; ++j) {
        float mx = fmaxf(fmaxf(sc[j][0], sc[j][1]), fmaxf(sc[j][2], sc[j][3]));
        float a0 = __expf(sc[j][0] - mx), a1 = __expf(sc[j][1] - mx);
        float a2 = __expf(sc[j][2] - mx), a3 = __expf(sc[j][3] - mx);
        float inv = 1.f / (a0 + a1 + a2 + a3);
        wsum[0] += a0 * inv; wsum[1] += a1 * inv; wsum[2] += a2 * inv; wsum[3] += a3 * inv;
      }

      prev = wsum[0] * V[0] + wsum[1] * V[1] + wsum[2] * V[2] + wsum[3] * V[3];
      __syncthreads();
    }
    atomicAdd(&tree_emb[b * 64 + e], prev);
  }
}

// ---------------------------------------------------------------------------
// Kernel 2: logits = [pooled_sum/4096 || tree_emb] @ fc_w  + clip(log(mask))
// grid 128 x 256
// ---------------------------------------------------------------------------
__global__ void k_final(const float* __restrict__ action_mask, const float* __restrict__ fc_w,
                        const float* __restrict__ pooled_sum, const float* __restrict__ tree_emb,
                        float* __restrict__ out) {
  __shared__ float c[128];
  const int b = blockIdx.x >> 4;
  const int a = ((blockIdx.x & 15) << 8) + threadIdx.x;
  if (threadIdx.x < 128) {
    c[threadIdx.x] = (threadIdx.x < 64) ? pooled_sum[b * 64 + threadIdx.x] * (1.f / 4096.f)
                                        : tree_emb[b * 64 + threadIdx.x - 64];
  }
  __syncthreads();
  float acc = 0.f;
  for (int i = 0; i < 128; ++i) acc += c[i] * fc_w[i * 4096 + a];
  const float m = action_mask[b * 4096 + a];
  float lg = __logf(m);
  lg = fminf(fmaxf(lg, -3.4e38f), 3.4e38f);
  out[b * 4096 + a] = lg + acc;
}

// ---------------------------------------------------------------------------
extern "C" void kernel_launch(void* const* d_in, const int* in_sizes, int n_in,
                              void* d_out, int out_size, void* d_ws, size_t ws_size,
                              hipStream_t stream) {
  const float* link = (const float*)d_in[0];
  const float* mask = (const float*)d_in[1];
  const float* col = (const float*)d_in[2];
  const float* rel = (const float*)d_in[3];
  const float* GW = (const float*)d_in[4];
  const float* gb = (const float*)d_in[5];
  const float* Wk = (const float*)d_in[6];
  const float* Wq = (const float*)d_in[7];
  const float* Wv = (const float*)d_in[8];
  const float* fcw = (const float*)d_in[9];
  const int* tids = (const int*)d_in[10];
  const int* lids = (const int*)d_in[11];
  const int* rids = (const int*)d_in[12];
  float* out = (float*)d_out;

  unsigned short* bTf = (unsigned short*)d_ws;              // 512 KB (frag-packed relGW)
  float* accums = (float*)((char*)d_ws + 512 * 1024);       // 1024 floats
  float* pooled_sum = accums;                               // [8][64]
  float* tree = accums + 512;                               // [8][64]

  hipLaunchKernelGGL(k_prep, dim3(64), dim3(256), 0, stream, rel, GW, bTf, accums);
  hipLaunchKernelGGL(k_main, dim3(528), dim3(256), 0, stream,
                     link, bTf, gb, pooled_sum,
                     col, rel, Wk, Wq, Wv, tids, lids, rids, tree);
  hipLaunchKernelGGL(k_final, dim3(128), dim3(256), 0, stream, mask, fcw, pooled_sum, tree, out);
}